// Round 4
// baseline (313.230 us; speedup 1.0000x reference)
//
#include <hip/hip_runtime.h>

#define BLOCK 256

__global__ __launch_bounds__(BLOCK) void edge_encoding_kernel(
    const float* __restrict__ pos,      // [N,3] f32
    const float* __restrict__ cells,    // [G,3,3] = 144 f32
    const int*  __restrict__ eidx,      // [2,E]
    const int*  __restrict__ pidx,      // [E]
    const int*  __restrict__ batch,     // [N]
    float* __restrict__ out,            // [E,19] f32
    int E)
{
    __shared__ float s_cells[144];
    __shared__ __align__(16) float s_out[BLOCK * 19];   // 19456 B

    const int tid = threadIdx.x;
    if (tid < 144) s_cells[tid] = cells[tid];
    __syncthreads();

    const int base = blockIdx.x * BLOCK;
    const int e = base + tid;

    float row[19];
    if (e < E) {
        const int src = eidx[e];
        const int dst = eidx[E + e];
        const int p   = pidx[e];
        const int g   = batch[src];

        const float sx = pos[3*src+0], sy = pos[3*src+1], sz = pos[3*src+2];
        const float dx = pos[3*dst+0], dy = pos[3*dst+1], dz = pos[3*dst+2];

        // periodic shift from index: p = i*9 + j*3 + k -> (i-1, j-1, k-1)
        const float f0 = (float)(p / 9 - 1);
        const float f1 = (float)((p / 3) % 3 - 1);
        const float f2 = (float)(p % 3 - 1);

        const float* C = s_cells + g * 9;
        // t_j = sum_i cell[i][j] * shift[i]
        const float tx = C[0]*f0 + C[3]*f1 + C[6]*f2;
        const float ty = C[1]*f0 + C[4]*f1 + C[7]*f2;
        const float tz = C[2]*f0 + C[5]*f1 + C[8]*f2;

        // v = -(pos[dst]-pos[src] - t) = pos[src] - pos[dst] + t
        const float vx = sx - dx + tx;
        const float vy = sy - dy + ty;
        const float vz = sz - dz + tz;

        const float len  = sqrtf(vx*vx + vy*vy + vz*vz);
        const float invl = 1.0f / fmaxf(len, 1e-6f);
        const float x = vx * invl, y = vy * invl, z = vz * invl;

        const float s3  = 1.7320508075688772f;
        const float s5  = 2.2360679774997896f;
        const float s15 = 3.872983346207417f;

        row[0] = len;
        row[1] = 1.0f;
        row[2] = s3 * x;
        row[3] = s3 * y;
        row[4] = s3 * z;
        row[5] = s15 * x * z;
        row[6] = s15 * x * y;
        row[7] = s5  * (y*y - 0.5f*(x*x + z*z));
        row[8] = s15 * y * z;
        row[9] = 0.5f * s15 * (z*z - x*x);

        // polynomial cutoff (P=6): 1 - 28 x^6 + 48 x^7 - 21 x^8
        const float xc = fminf(len * (1.0f/6.0f), 1.0f);
        const float x3 = xc * xc * xc;
        const float x6 = x3 * x3;
        const float cut = fmaf(x6, fmaf(xc, fmaf(-21.0f, xc, 48.0f), -28.0f), 1.0f);
        row[10] = cut;

        // bessel: sin(n*a)/(2*safe) * cut, a = safe*pi/6, n=1..8 (Chebyshev recurrence)
        const float safe = fminf(fmaxf(len, 1e-6f), 6.0f);
        const float a = safe * 0.5235987755982988f;   // pi/6
        float sa, ca;
        sincosf(a, &sa, &ca);                          // precise variant
        const float w = cut / (2.0f * safe);
        const float two_ca = 2.0f * ca;
        float s_prev = 0.0f, s_cur = sa;
        row[11] = s_cur * w;
        #pragma unroll
        for (int n = 2; n <= 8; ++n) {
            const float s_next = two_ca * s_cur - s_prev;
            s_prev = s_cur;
            s_cur  = s_next;
            row[10 + n] = s_cur * w;
        }
    } else {
        #pragma unroll
        for (int j = 0; j < 19; ++j) row[j] = 0.0f;
    }

    // stride-19 writes: gcd(19,32)=1 -> bank-conflict-free
    #pragma unroll
    for (int j = 0; j < 19; ++j) s_out[tid * 19 + j] = row[j];
    __syncthreads();

    // coalesced copy LDS -> global in float4 chunks
    const int nvalid  = min(BLOCK, E - base);
    const int nfloats = nvalid * 19;
    float* gout = out + (size_t)base * 19;            // 19456-byte multiple: 16B aligned
    const int n4 = nfloats >> 2;
    const float4* s4 = reinterpret_cast<const float4*>(s_out);
    float4* g4 = reinterpret_cast<float4*>(gout);
    for (int i = tid; i < n4; i += BLOCK) g4[i] = s4[i];
    for (int i = (n4 << 2) + tid; i < nfloats; i += BLOCK) gout[i] = s_out[i];
}

extern "C" void kernel_launch(void* const* d_in, const int* in_sizes, int n_in,
                              void* d_out, int out_size, void* d_ws, size_t ws_size,
                              hipStream_t stream) {
    const float* pos   = (const float*)d_in[0];
    const float* cells = (const float*)d_in[1];
    const int*   eidx  = (const int*)d_in[2];
    const int*   pidx  = (const int*)d_in[3];
    const int*   batch = (const int*)d_in[4];
    float* out = (float*)d_out;

    const int E = in_sizes[3];   // periodic_index count = num edges
    const int grid = (E + BLOCK - 1) / BLOCK;
    edge_encoding_kernel<<<grid, BLOCK, 0, stream>>>(pos, cells, eidx, pidx, batch, out, E);
}